// Round 17
// baseline (99.037 us; speedup 1.0000x reference)
//
#include <hip/hip_runtime.h>

// Problem constants (fixed by setup_inputs).
constexpr int L  = 512;   // sequence length
constexpr int CS = 384;   // c_s
constexpr int CH = 32;    // c_h
constexpr int CZ = 128;   // c_z
constexpr float LN_EPS = 1e-5f;

typedef float f2 __attribute__((ext_vector_type(2)));
typedef float f4 __attribute__((ext_vector_type(4)));

// ---------------------------------------------------------------------------
// Kernel 1 (v2): LayerNorm + dual projection + mask.  (R11-exact)
// ---------------------------------------------------------------------------
__global__ __launch_bounds__(64) void k_ln_proj(
    const float* __restrict__ s, const int* __restrict__ mask,
    const float* __restrict__ ln_scale, const float* __restrict__ ln_bias,
    const float* __restrict__ w1, const float* __restrict__ b1,
    const float* __restrict__ w2, const float* __restrict__ b2,
    float* __restrict__ a, float* __restrict__ b)
{
    __shared__ float sn_lds[CS];
    const int lane = threadIdx.x;
    const int row  = blockIdx.x;

    const float* srow = s + row * CS;
    float v[6];
    float sum = 0.f, sumsq = 0.f;
#pragma unroll
    for (int q = 0; q < 6; ++q) {
        v[q] = srow[lane + 64 * q];
        sum   += v[q];
        sumsq += v[q] * v[q];
    }
#pragma unroll
    for (int off = 32; off; off >>= 1) {
        sum   += __shfl_xor(sum, off);
        sumsq += __shfl_xor(sumsq, off);
    }
    const float mu   = sum * (1.f / CS);
    const float var  = sumsq * (1.f / CS) - mu * mu;
    const float rstd = rsqrtf(var + LN_EPS);
#pragma unroll
    for (int q = 0; q < 6; ++q) {
        const int k = lane + 64 * q;
        sn_lds[k] = (v[q] - mu) * rstd * ln_scale[k] + ln_bias[k];
    }
    __syncthreads();

    const int c    = lane & 31;
    const int half = lane >> 5;
    const float* W  = half ? w2 : w1;
    const float* Bv = half ? b2 : b1;
    float acc = 0.f;
#pragma unroll 4
    for (int k = 0; k < CS; ++k)
        acc += sn_lds[k] * W[k * CH + c];
    const float m = (float)mask[row];
    const float outv = (acc + Bv[c]) * m;
    (half ? b : a)[row * CH + c] = outv;
}

// ---------------------------------------------------------------------------
// Kernel 2: G[i][e][z] = sum_c a[i][c] * w_out[(c*CH+e)*CZ + z].  (R15-exact)
// ---------------------------------------------------------------------------
__global__ __launch_bounds__(512) void k_G(
    const float* __restrict__ a, const float* __restrict__ w_out,
    float* __restrict__ G)
{
    const int i0 = blockIdx.x * 2;
    const int t  = threadIdx.x;
    const int e  = t >> 4;             // 0..31
    const int zo = t & 15;             // z-octet: z = 8*zo .. 8*zo+7

    float a0[CH], a1[CH];
#pragma unroll
    for (int c = 0; c < CH; ++c) {
        a0[c] = a[i0 * CH + c];        // wave-uniform -> broadcast
        a1[c] = a[(i0 + 1) * CH + c];
    }

    const float* wbase = w_out + (size_t)e * CZ + 8 * zo;   // + c*CH*CZ per c
    f4 g00 = 0.f, g01 = 0.f, g10 = 0.f, g11 = 0.f;
#pragma unroll
    for (int c = 0; c < CH; ++c) {
        const f4 w0 = *(const f4*)(wbase + (size_t)c * (CH * CZ));
        const f4 w1 = *(const f4*)(wbase + (size_t)c * (CH * CZ) + 4);
        g00 += a0[c] * w0;  g01 += a0[c] * w1;
        g10 += a1[c] * w0;  g11 += a1[c] * w1;
    }

    float* Gp0 = G + (size_t)i0 * (CH * CZ) + e * CZ + 8 * zo;
    *(f4*)(Gp0)     = g00;
    *(f4*)(Gp0 + 4) = g01;
    float* Gp1 = Gp0 + CH * CZ;
    *(f4*)(Gp1)     = g10;
    *(f4*)(Gp1 + 4) = g11;
}

// ---------------------------------------------------------------------------
// Kernel 3 (A/B probe, templated destination):  R16-EXACT compute/structure.
// DEST=ws2 for the A-dispatch (measures the identical store stream into
// d_ws), DEST=out for the B-dispatch (correctness; overwrites nothing of A).
// Total - 72.4us (R16: ln+G+mainOUT+ovh) = mainWS directly.
// ---------------------------------------------------------------------------
__global__ __launch_bounds__(512, 2) void k_main(
    const float* __restrict__ b, const float* __restrict__ G,
    const float* __restrict__ b_out, float* __restrict__ dest)
{
    __shared__ float b_lds[L][CH];     // 64 KB: entire b matrix

    const int i    = blockIdx.x;
    const int t    = threadIdx.x;
    const int wave = t >> 6;
    const int lane = t & 63;
    const int half = lane >> 5;        // which j of the wave's pair
    const int zq   = lane & 31;        // z-quad: z = 4*zq

    // Stage all of b: 16384 floats = 512 threads x 8 float4.
#pragma unroll
    for (int k = 0; k < 8; ++k)
        ((f4*)b_lds)[t + k * 512] = ((const f4*)b)[t + k * 512];

    // G[i] z-quad column for this lane: 128 VGPRs (f4-coalesced, L2/L3-hot).
    f4 G_reg[CH];
    const float* Gi = G + (size_t)i * (CH * CZ) + 4 * zq;
#pragma unroll
    for (int e = 0; e < CH; ++e)
        G_reg[e] = *(const f4*)(Gi + e * CZ);

    const f4 bo = ((const f4*)b_out)[zq];
    float* op = dest + (size_t)i * (L * CZ);

    __syncthreads();

#pragma unroll 2
    for (int s = 0; s < 32; ++s) {
        const int j = s * 16 + 2 * wave + half;
        const f4* bp = (const f4*)&b_lds[j][0];   // 2-way row split (free)
        f4 acc = bo;
#pragma unroll
        for (int q = 0; q < 8; ++q) {
            const f4 r = bp[q];
            acc += r.x * G_reg[4 * q + 0];
            acc += r.y * G_reg[4 * q + 1];
            acc += r.z * G_reg[4 * q + 2];
            acc += r.w * G_reg[4 * q + 3];
        }
        *(f4*)(op + (size_t)j * CZ + 4 * zq) = acc;
    }
}

// ---------------------------------------------------------------------------
extern "C" void kernel_launch(void* const* d_in, const int* in_sizes, int n_in,
                              void* d_out, int out_size, void* d_ws, size_t ws_size,
                              hipStream_t stream) {
    const float* s        = (const float*)d_in[0];
    const int*   mask     = (const int*)d_in[1];
    const float* ln_scale = (const float*)d_in[2];
    const float* ln_bias  = (const float*)d_in[3];
    const float* w1       = (const float*)d_in[4];
    const float* b1       = (const float*)d_in[5];
    const float* w2       = (const float*)d_in[6];
    const float* b2       = (const float*)d_in[7];
    const float* w_out    = (const float*)d_in[8];
    const float* b_out    = (const float*)d_in[9];
    float* out = (float*)d_out;

    // Workspace: a [16K], b [16K], G [2M floats], ws2 mirror [33.5M floats].
    float* a   = (float*)d_ws;
    float* b   = a + L * CH;
    float* G   = b + L * CH;
    float* ws2 = G + (size_t)L * CH * CZ;

    k_ln_proj<<<L, 64, 0, stream>>>(s, mask, ln_scale, ln_bias,
                                    w1, b1, w2, b2, a, b);
    k_G<<<L / 2, 512, 0, stream>>>(a, w_out, G);
    // A: identical store stream into d_ws (diagnostic).
    k_main<<<L, 512, 0, stream>>>(b, G, b_out, ws2);
    // B: R16-exact, writes d_out (correctness).
    k_main<<<L, 512, 0, stream>>>(b, G, b_out, out);
}

// Round 18
// 73.313 us; speedup vs baseline: 1.3509x; 1.3509x over previous
//
#include <hip/hip_runtime.h>

// Problem constants (fixed by setup_inputs).
constexpr int L  = 512;   // sequence length
constexpr int CS = 384;   // c_s
constexpr int CH = 32;    // c_h
constexpr int CZ = 128;   // c_z
constexpr float LN_EPS = 1e-5f;

typedef float f2 __attribute__((ext_vector_type(2)));
typedef float f4 __attribute__((ext_vector_type(4)));

// ---------------------------------------------------------------------------
// Kernel 1 (v2): LayerNorm + dual projection + mask.  (R11-exact)
// ---------------------------------------------------------------------------
__global__ __launch_bounds__(64) void k_ln_proj(
    const float* __restrict__ s, const int* __restrict__ mask,
    const float* __restrict__ ln_scale, const float* __restrict__ ln_bias,
    const float* __restrict__ w1, const float* __restrict__ b1,
    const float* __restrict__ w2, const float* __restrict__ b2,
    float* __restrict__ a, float* __restrict__ b)
{
    __shared__ float sn_lds[CS];
    const int lane = threadIdx.x;
    const int row  = blockIdx.x;

    const float* srow = s + row * CS;
    float v[6];
    float sum = 0.f, sumsq = 0.f;
#pragma unroll
    for (int q = 0; q < 6; ++q) {
        v[q] = srow[lane + 64 * q];
        sum   += v[q];
        sumsq += v[q] * v[q];
    }
#pragma unroll
    for (int off = 32; off; off >>= 1) {
        sum   += __shfl_xor(sum, off);
        sumsq += __shfl_xor(sumsq, off);
    }
    const float mu   = sum * (1.f / CS);
    const float var  = sumsq * (1.f / CS) - mu * mu;
    const float rstd = rsqrtf(var + LN_EPS);
#pragma unroll
    for (int q = 0; q < 6; ++q) {
        const int k = lane + 64 * q;
        sn_lds[k] = (v[q] - mu) * rstd * ln_scale[k] + ln_bias[k];
    }
    __syncthreads();

    const int c    = lane & 31;
    const int half = lane >> 5;
    const float* W  = half ? w2 : w1;
    const float* Bv = half ? b2 : b1;
    float acc = 0.f;
#pragma unroll 4
    for (int k = 0; k < CS; ++k)
        acc += sn_lds[k] * W[k * CH + c];
    const float m = (float)mask[row];
    const float outv = (acc + Bv[c]) * m;
    (half ? b : a)[row * CH + c] = outv;
}

// ---------------------------------------------------------------------------
// Kernel 2: G[i][e][z] = sum_c a[i][c] * w_out[(c*CH+e)*CZ + z].  (R15-exact)
// ---------------------------------------------------------------------------
__global__ __launch_bounds__(512) void k_G(
    const float* __restrict__ a, const float* __restrict__ w_out,
    float* __restrict__ G)
{
    const int i0 = blockIdx.x * 2;
    const int t  = threadIdx.x;
    const int e  = t >> 4;             // 0..31
    const int zo = t & 15;             // z-octet: z = 8*zo .. 8*zo+7

    float a0[CH], a1[CH];
#pragma unroll
    for (int c = 0; c < CH; ++c) {
        a0[c] = a[i0 * CH + c];        // wave-uniform -> broadcast
        a1[c] = a[(i0 + 1) * CH + c];
    }

    const float* wbase = w_out + (size_t)e * CZ + 8 * zo;   // + c*CH*CZ per c
    f4 g00 = 0.f, g01 = 0.f, g10 = 0.f, g11 = 0.f;
#pragma unroll
    for (int c = 0; c < CH; ++c) {
        const f4 w0 = *(const f4*)(wbase + (size_t)c * (CH * CZ));
        const f4 w1 = *(const f4*)(wbase + (size_t)c * (CH * CZ) + 4);
        g00 += a0[c] * w0;  g01 += a0[c] * w1;
        g10 += a1[c] * w0;  g11 += a1[c] * w1;
    }

    float* Gp0 = G + (size_t)i0 * (CH * CZ) + e * CZ + 8 * zo;
    *(f4*)(Gp0)     = g00;
    *(f4*)(Gp0 + 4) = g01;
    float* Gp1 = Gp0 + CH * CZ;
    *(f4*)(Gp1)     = g10;
    *(f4*)(Gp1 + 4) = g11;
}

// ---------------------------------------------------------------------------
// Kernel 3 (v6): z[i,j,:] = sum_e b[j,e] * G[i,e,:] + b_out.
// BURST-STORE design. R17 proved the identical compute runs 27 us when the
// destination is d_ws but ~62 us into d_out; R13 proved d_out takes 7.1 TB/s
// from a pure-store kernel with ~1 MB/CU of stores in flight. Model: d_out
// stores bypass L2 (fine-grained semantics) -> throughput scales with
// OUTSTANDING stores, and compute-paced emission (1 KB per ~50 cyc/wave)
// starves the queue. Fix: decouple — each wave computes 8 j-rows into
// registers (acc[8], 32 VGPR), then fires 8 back-to-back f4 stores = 8 KB
// contiguous per burst (sched_barrier keeps the burst tight). In-flight
// bytes at store time rise ~8x. Everything else is R16-exact: block = one
// i (linear 256 KB sweep of out[i]), G z-quad in 128 VGPR, b fully in LDS,
// full-wave uniform b-row broadcasts (conflict-free).
// ---------------------------------------------------------------------------
__global__ __launch_bounds__(512, 2) void k_main(
    const float* __restrict__ b, const float* __restrict__ G,
    const float* __restrict__ b_out, float* __restrict__ out)
{
    __shared__ float b_lds[L][CH];     // 64 KB: entire b matrix

    const int i    = blockIdx.x;
    const int t    = threadIdx.x;
    const int wave = t >> 6;
    const int lane = t & 63;
    const int zq   = lane & 31;        // z-quad: z = 4*zq (lanes 32..63 mirror)

    // Stage all of b: 16384 floats = 512 threads x 8 float4.
#pragma unroll
    for (int k = 0; k < 8; ++k)
        ((f4*)b_lds)[t + k * 512] = ((const f4*)b)[t + k * 512];

    // G[i] z-quad column: lanes 0-31 cover z=0..127; lanes 32-63 duplicate
    // (each half-wave stores a full row half? no: both halves store same zq
    //  for different j's below — half picks the j offset).
    const int half = lane >> 5;
    f4 G_reg[CH];
    const float* Gi = G + (size_t)i * (CH * CZ) + 4 * zq;
#pragma unroll
    for (int e = 0; e < CH; ++e)
        G_reg[e] = *(const f4*)(Gi + e * CZ);

    const f4 bo = ((const f4*)b_out)[zq];
    float* op = out + (size_t)i * (L * CZ);

    __syncthreads();

    // 8 bursts; per burst a wave handles 8 consecutive j-PAIRS? No: wave
    // handles 8 consecutive j's split as (j0 + 2u + half) so each half-wave
    // covers 4 rows and a wave-store of acc[u] is 1 KB contiguous (2 rows).
    for (int bs = 0; bs < 8; ++bs) {
        const int j0 = bs * 64 + wave * 8;   // this wave's 8 rows this burst
        f4 acc[4];
        // ---- compute phase: 4 accs (each = one j per half-wave) ----
#pragma unroll
        for (int u = 0; u < 4; ++u) {
            const int j = j0 + 2 * u + half;
            const f4* bp = (const f4*)&b_lds[j][0];   // 2-way row split (free)
            f4 a = bo;
#pragma unroll
            for (int q = 0; q < 8; ++q) {
                const f4 r = bp[q];
                a += r.x * G_reg[4 * q + 0];
                a += r.y * G_reg[4 * q + 1];
                a += r.z * G_reg[4 * q + 2];
                a += r.w * G_reg[4 * q + 3];
            }
            acc[u] = a;
        }
        __builtin_amdgcn_sched_barrier(0);
        // ---- store phase: 4 back-to-back wave stores = 4 KB contiguous ----
#pragma unroll
        for (int u = 0; u < 4; ++u) {
            const int j = j0 + 2 * u + half;
            *(f4*)(op + (size_t)j * CZ + 4 * zq) = acc[u];
        }
        __builtin_amdgcn_sched_barrier(0);
    }
}

// ---------------------------------------------------------------------------
extern "C" void kernel_launch(void* const* d_in, const int* in_sizes, int n_in,
                              void* d_out, int out_size, void* d_ws, size_t ws_size,
                              hipStream_t stream) {
    const float* s        = (const float*)d_in[0];
    const int*   mask     = (const int*)d_in[1];
    const float* ln_scale = (const float*)d_in[2];
    const float* ln_bias  = (const float*)d_in[3];
    const float* w1       = (const float*)d_in[4];
    const float* b1       = (const float*)d_in[5];
    const float* w2       = (const float*)d_in[6];
    const float* b2       = (const float*)d_in[7];
    const float* w_out    = (const float*)d_in[8];
    const float* b_out    = (const float*)d_in[9];
    float* out = (float*)d_out;

    // Workspace: a [512*32], b [512*32], G [512*32*128]  (8.125 MB total).
    float* a = (float*)d_ws;
    float* b = a + L * CH;
    float* G = b + L * CH;

    k_ln_proj<<<L, 64, 0, stream>>>(s, mask, ln_scale, ln_bias,
                                    w1, b1, w2, b2, a, b);
    k_G<<<L / 2, 512, 0, stream>>>(a, w_out, G);
    k_main<<<L, 512, 0, stream>>>(b, G, b_out, out);
}